// Round 9
// baseline (199.894 us; speedup 1.0000x reference)
//
#include <hip/hip_runtime.h>
#include <hip/hip_bf16.h>

#define M_TOTAL 65536
#define DIM 768
#define KC 64
#define INV_T 10.0f

// k_weighted tiling
#define DT 128    // d-cols per block
#define MB 64     // m per LDS chunk
#define CH 8      // chunks per block (m-range 512)
#define MSEG 128  // m-segments (partials)

#define LOGITS_BLOCKS (M_TOTAL / 64)   // 1024 (64 rows per block)
#define SROWS 128
#define SINK_BLOCKS (M_TOTAL / SROWS)  // 512

typedef __attribute__((ext_vector_type(4))) float f32x4;
typedef __attribute__((ext_vector_type(8))) short bf16x8;
typedef __attribute__((ext_vector_type(4))) unsigned short u16x4;

__device__ __forceinline__ short f2bf(float f) {
    __hip_bfloat16 h = __float2bfloat16(f);
    union { __hip_bfloat16 h; short s; } u; u.h = h;
    return u.s;
}

// ---------------- K0: normalize centers -> cn (fp32) + cnbf (bf16) ----------------
__global__ __launch_bounds__(256) void k_centers(const float* __restrict__ centers,
                                                 float* __restrict__ cn,
                                                 short* __restrict__ cnbf) {
    int k = blockIdx.x, tid = threadIdx.x;
    float ss = 0.f;
    for (int i = tid; i < DIM; i += 256) { float v = centers[k * DIM + i]; ss += v * v; }
    __shared__ float red[4];
    for (int o = 32; o; o >>= 1) ss += __shfl_xor(ss, o);
    if ((tid & 63) == 0) red[tid >> 6] = ss;
    __syncthreads();
    ss = red[0] + red[1] + red[2] + red[3];
    float inv = 1.0f / fmaxf(sqrtf(ss), 1e-12f);
    for (int i = tid; i < DIM; i += 256) {
        float v = centers[k * DIM + i] * inv;
        cn[k * DIM + i] = v;
        cnbf[k * DIM + i] = f2bf(v);
    }
}

// ---------------- K1: logits GEMM — 3-buffer counted-vmcnt pipeline ---------------
// Per tile iter: [s_waitcnt vmcnt(4); s_barrier; sched_barrier; Bpf(t+1)->regs;
// stage(t+2)->LDS; compute(t)]. B loads issued BEFORE F staging so the compiler's
// B-wait never drains the F prefetch (vmcnt retires in issue order). One barrier
// per tile; tile t's F loads issued 2 iters ahead. E stored pre-swizzled for sinks.
__global__ __launch_bounds__(256) void k_logits(const float* __restrict__ F,
                                                const short* __restrict__ cnbf,
                                                float* __restrict__ E,
                                                float* __restrict__ invn,
                                                float* __restrict__ PS0) {
    __shared__ float fbuf[3][4096];  // 48 KiB, [row 0..63][col 0..63] swizzled-by-source
    __shared__ float bsr[4][KC];
    int tid = threadIdx.x;
    int wave = tid >> 6, lane = tid & 63;
    int l15 = lane & 15, lhi = lane >> 4;
    int rowbase = blockIdx.x * 64;

    int srow = tid >> 4;       // staging row 0..15 (+16 per issue)
    int c4 = (tid & 15) * 4;   // staging col group

#define STAGE(t_, b_)                                                                     \
    do {                                                                                  \
        _Pragma("unroll") for (int i_ = 0; i_ < 4; ++i_) {                                \
            int row_ = i_ * 16 + srow;                                                    \
            const float* src_ = F + (size_t)(rowbase + row_) * DIM + (t_) * 64            \
                                + (c4 ^ ((row_ & 7) << 2));                               \
            float* dst_ = &fbuf[b_][i_ * 1024 + wave * 256];                              \
            __builtin_amdgcn_global_load_lds(                                             \
                (const __attribute__((address_space(1))) void*)src_,                      \
                (__attribute__((address_space(3))) void*)dst_, 16, 0, 0);                 \
        }                                                                                 \
    } while (0)

    const short* Bb = cnbf + (size_t)l15 * DIM + lhi * 8;
#define BLOAD(t_, br_)                                                                    \
    do {                                                                                  \
        _Pragma("unroll") for (int n_ = 0; n_ < 4; ++n_) {                                \
            br_[n_ * 2]     = *(const bf16x8*)(Bb + (size_t)n_ * 16 * DIM + (t_) * 64);   \
            br_[n_ * 2 + 1] = *(const bf16x8*)(Bb + (size_t)n_ * 16 * DIM + (t_) * 64 + 32); \
        }                                                                                 \
    } while (0)

    bf16x8 bA[8], bB[8];
    BLOAD(0, bA);      // 8 loads (oldest)
    STAGE(0, 0);       // 4
    STAGE(1, 1);       // 4

    f32x4 acc[4];
#pragma unroll
    for (int n = 0; n < 4; ++n) acc[n] = (f32x4){0.f, 0.f, 0.f, 0.f};
    float ss = 0.f;

    int myrow = wave * 16 + l15;
    int swz = (l15 & 7) << 2;

#pragma unroll
    for (int t = 0; t < 12; ++t) {
        // own tile-t F loads done (<=4 newest outstanding = next stage), then all waves'
        asm volatile("s_waitcnt vmcnt(4)" ::: "memory");
        __builtin_amdgcn_s_barrier();
        __builtin_amdgcn_sched_barrier(0);
        bf16x8* bc = (t & 1) ? bB : bA;
        bf16x8* bn = (t & 1) ? bA : bB;
        if (t + 1 < 12) BLOAD(t + 1, bn);       // B first (issue order matters)
        if (t + 2 < 12) STAGE(t + 2, (t + 2) % 3);
        const float* cb = fbuf[t % 3] + myrow * 64;
#pragma unroll
        for (int kk = 0; kk < 2; ++kk) {
            int c0s = (kk * 32 + lhi * 8) ^ swz;
            f32x4 fa = *(const f32x4*)(cb + c0s);
            f32x4 fb2 = *(const f32x4*)(cb + (c0s ^ 4));
            ss += fa[0] * fa[0] + fa[1] * fa[1] + fa[2] * fa[2] + fa[3] * fa[3]
                + fb2[0] * fb2[0] + fb2[1] * fb2[1] + fb2[2] * fb2[2] + fb2[3] * fb2[3];
            bf16x8 af;
            af[0] = f2bf(fa[0]); af[1] = f2bf(fa[1]); af[2] = f2bf(fa[2]); af[3] = f2bf(fa[3]);
            af[4] = f2bf(fb2[0]); af[5] = f2bf(fb2[1]); af[6] = f2bf(fb2[2]); af[7] = f2bf(fb2[3]);
#pragma unroll
            for (int n = 0; n < 4; ++n)
                acc[n] = __builtin_amdgcn_mfma_f32_16x16x32_bf16(af, bc[n * 2 + kk], acc[n], 0, 0, 0);
        }
    }
#undef STAGE
#undef BLOAD

    // ---- per-wave epilogue ----
    ss += __shfl_xor(ss, 16);
    ss += __shfl_xor(ss, 32);
    float inv = 1.0f / fmaxf(sqrtf(ss), 1e-12f);
    int growbase = rowbase + wave * 16;
    if (lane < 16) invn[growbase + lane] = inv;

    float sc[4];
#pragma unroll
    for (int j = 0; j < 4; ++j) sc[j] = __shfl(inv, lhi * 4 + j) * INV_T;

    float colp[4] = {0.f, 0.f, 0.f, 0.f};
#pragma unroll
    for (int n = 0; n < 4; ++n) {
#pragma unroll
        for (int j = 0; j < 4; ++j) {
            float e = expf(acc[n][j] * sc[j]);
            int row = lhi * 4 + j;  // row & 15
            E[(size_t)(growbase + row) * KC + ((n * 16 + l15) ^ (row << 2))] = e;
            colp[n] += e;
        }
    }
#pragma unroll
    for (int n = 0; n < 4; ++n) {
        colp[n] += __shfl_xor(colp[n], 16);
        colp[n] += __shfl_xor(colp[n], 32);
    }
    __syncthreads();  // bsr reuse safe (fbuf distinct); all waves done with loop barriers
    if (lane < 16) {
#pragma unroll
        for (int n = 0; n < 4; ++n) bsr[wave][n * 16 + lane] = colp[n];
    }
    __syncthreads();
    if (tid < KC) PS0[(size_t)blockIdx.x * KC + tid] =
        bsr[0][tid] + bsr[1][tid] + bsr[2][tid] + bsr[3][tid];
}

// ---------------- k_redR: reduce per-block partials + compute R scale -------------
template <int STAGE>
__global__ __launch_bounds__(1024) void k_redR(const float* __restrict__ PS, int nblocks,
                                               const float* __restrict__ Rin,
                                               float* __restrict__ Rout) {
    __shared__ float part[16][KC];
    int k = threadIdx.x & 63, g = threadIdx.x >> 6;
    float s = 0.f;
    for (int p = g; p < nblocks; p += 16) s += PS[(size_t)p * KC + k];
    part[g][k] = s;
    __syncthreads();
    if (threadIdx.x < KC) {
        float sk = 0.f;
#pragma unroll
        for (int g2 = 0; g2 < 16; ++g2) sk += part[g2][k];
        if (STAGE == 0) {
            float tot = sk;
            for (int o = 32; o; o >>= 1) tot += __shfl_xor(tot, o);
            float S = fmaxf(tot, 1e-12f);
            Rout[k] = (1.0f / S) / (fmaxf(sk / S, 1e-12f) * 64.0f);
        } else {
            float r = Rin[k];
            Rout[k] = r / (fmaxf(r * sk, 1e-12f) * 64.0f);
        }
    }
}

// ---------------- P: sink pass, shuffle-free (LDS-based row sums) -----------------
template <int MODE>
__global__ __launch_bounds__(256) void k_sink(const float* __restrict__ E,
                                              const float* __restrict__ R,
                                              const float* __restrict__ invn,
                                              float* __restrict__ c,
                                              float* __restrict__ PS,
                                              float* __restrict__ Aout,
                                              short* __restrict__ Qbf) {
    __shared__ float tile[SROWS * KC];  // 32 KiB
    __shared__ float sbuf[SROWS];
    __shared__ float Rlds[KC];
    __shared__ float bacc[4][KC];
    int tid = threadIdx.x, lane = tid & 63, wave = tid >> 6;
    int m0 = blockIdx.x * SROWS;

    if (tid < KC) Rlds[tid] = R[tid];

    // phase 1: stage E rows (memory layout already swizzled -> linear copy)
#pragma unroll
    for (int i = 0; i < 8; ++i) {
        const float* src = E + (size_t)(m0 + i * 16 + wave * 4 + (lane >> 4)) * KC + (lane & 15) * 4;
        float* dst = tile + (i * 16 + wave * 4) * KC;
        __builtin_amdgcn_global_load_lds((const __attribute__((address_space(1))) void*)src,
                                         (__attribute__((address_space(3))) void*)dst, 16, 0, 0);
    }
    __syncthreads();

    // phase 1.5: v = e * R[k]   (k = col ^ swizzle(row))
#pragma unroll
    for (int i = 0; i < 32; ++i) {
        int idx = tid + i * 256;
        int mloc = idx >> 6, ccol = idx & 63;
        tile[idx] *= Rlds[ccol ^ ((mloc & 15) << 2)];
    }
    __syncthreads();

    // phase 2: row sums of v (thread-per-row, XOR-ordered vector reads)
    if (tid < SROWS) {
        const float* rp = tile + tid * KC;
        int sw = tid & 15;
        f32x4 a0 = {0.f, 0.f, 0.f, 0.f}, a1 = {0.f, 0.f, 0.f, 0.f};
#pragma unroll
        for (int j = 0; j < 16; j += 2) {
            a0 += *(const f32x4*)(rp + ((j ^ sw) << 2));
            a1 += *(const f32x4*)(rp + (((j + 1) ^ sw) << 2));
        }
        f32x4 a = a0 + a1;
        sbuf[tid] = a[0] + a[1] + a[2] + a[3];
    }
    __syncthreads();

    // phase 3: lane = k; 32 rows per wave
    float wacc = 0.f;
    int rbase = wave * 32;
#pragma unroll 4
    for (int r = 0; r < 32; ++r) {
        int rr = rbase + r;
        int m = m0 + rr;
        float v = tile[rr * KC + (lane ^ ((rr & 15) << 2))];
        float s = sbuf[rr];
        float cold = (MODE == 0) ? 1.0f : c[m];
        float cnew = cold / (fmaxf(cold * s, 1e-12f) * 65536.0f);
        if (MODE == 2) {
            float a = v * cnew * 65536.0f;
            size_t idx = (size_t)m * KC + lane;
            Aout[idx] = a;
            Qbf[idx] = f2bf(a * invn[m]);
            wacc += a;
        } else {
            if (lane == 0) c[m] = cnew;
            wacc += v * cnew;  // = (e*R)*cnew ; divided by R[k] below
        }
    }
    bacc[wave][lane] = wacc;
    __syncthreads();
    if (tid < KC) {
        float ps = bacc[0][tid] + bacc[1][tid] + bacc[2][tid] + bacc[3][tid];
        if (MODE != 2) ps /= Rlds[tid];
        PS[(size_t)blockIdx.x * KC + tid] = ps;
    }
}

// ---------------- K3: weighted centers — bf16 MFMA GEMM, prefetched ---------------
__global__ __launch_bounds__(256) void k_weighted(const float* __restrict__ F,
                                                  const short* __restrict__ Qbf,
                                                  float* __restrict__ P) {
    __shared__ short ldsF[DT * MB];  // [d][m] swizzled, 16 KiB
    __shared__ short ldsQ[KC * MB];  // [k][m] swizzled, 8 KiB
    int tid = threadIdx.x;
    int dt = blockIdx.x;  // 0..5
    int ms = blockIdx.y;  // 0..MSEG-1
    int wave = tid >> 6, lane = tid & 63;
    int l15 = lane & 15, lhi = lane >> 4;

    int m0 = ms * (MB * CH);
    int d0 = dt * DT;

    f32x4 acc[4][2];
#pragma unroll
    for (int kt = 0; kt < 4; ++kt)
#pragma unroll
        for (int ds = 0; ds < 2; ++ds) acc[kt][ds] = (f32x4){0.f, 0.f, 0.f, 0.f};

    int f_dq = (tid & 31) * 4;        // d 0..124 (float4 loads)
    int f_m8 = (tid >> 5) * 8;        // m 0..56
    int q_kq = (tid & 15) * 4;        // k 0..60   (threads <128)
    int q_m8 = ((tid >> 4) & 7) * 8;  // m 0..56

    float4 rf[8];
    u16x4 q[8];
#define LOADCH(mb_)                                                                       \
    do {                                                                                  \
        _Pragma("unroll") for (int j = 0; j < 8; ++j)                                     \
            rf[j] = *(const float4*)(F + (size_t)((mb_) + f_m8 + j) * DIM + d0 + f_dq);   \
        if (tid < 128) {                                                                  \
            _Pragma("unroll") for (int j = 0; j < 8; ++j)                                 \
                q[j] = *(const u16x4*)(Qbf + (size_t)((mb_) + q_m8 + j) * KC + q_kq);     \
        }                                                                                 \
    } while (0)

    LOADCH(m0);
    for (int ch = 0; ch < CH; ++ch) {
        __syncthreads();  // previous chunk's LDS reads done before overwrite
#pragma unroll
        for (int i = 0; i < 4; ++i) {
            int d = f_dq + i;
            uint4 w;
            w.x = (unsigned)(unsigned short)f2bf(rf[0][i]) | ((unsigned)(unsigned short)f2bf(rf[1][i]) << 16);
            w.y = (unsigned)(unsigned short)f2bf(rf[2][i]) | ((unsigned)(unsigned short)f2bf(rf[3][i]) << 16);
            w.z = (unsigned)(unsigned short)f2bf(rf[4][i]) | ((unsigned)(unsigned short)f2bf(rf[5][i]) << 16);
            w.w = (unsigned)(unsigned short)f2bf(rf[6][i]) | ((unsigned)(unsigned short)f2bf(rf[7][i]) << 16);
            int byte = (d * (MB * 2) + f_m8 * 2) ^ ((d & 7) << 4);
            *(uint4*)((char*)ldsF + byte) = w;
        }
        if (tid < 128) {
#pragma unroll
            for (int i = 0; i < 4; ++i) {
                int k = q_kq + i;
                uint4 w;
                w.x = (unsigned)q[0][i] | ((unsigned)q[1][i] << 16);
                w.y = (unsigned)q[2][i] | ((unsigned)q[3][i] << 16);
                w.z = (unsigned)q[4][i] | ((unsigned)q[5][i] << 16);
                w.w = (unsigned)q[6][i] | ((unsigned)q[7][i] << 16);
                int byte = (k * (MB * 2) + q_m8 * 2) ^ ((k & 7) << 4);
                *(uint4*)((char*)ldsQ + byte) = w;
            }
        }
        __syncthreads();
        if (ch + 1 < CH) LOADCH(m0 + (ch + 1) * MB);  // prefetch overlaps MFMA below
#pragma unroll
        for (int h = 0; h < 2; ++h) {
            bf16x8 afr[4];
#pragma unroll
            for (int kt = 0; kt < 4; ++kt) {
                int k = kt * 16 + l15;
                int byte = (k * (MB * 2) + (h * 32 + lhi * 8) * 2) ^ ((k & 7) << 4);
                afr[kt] = *(bf16x8*)((char*)ldsQ + byte);
            }
#pragma unroll
            for (int ds = 0; ds < 2; ++ds) {
                int d = wave * 32 + ds * 16 + l15;
                int byte = (d * (MB * 2) + (h * 32 + lhi * 8) * 2) ^ ((d & 7) << 4);
                bf16x8 bfr = *(bf16x8*)((char*)ldsF + byte);
#pragma unroll
                for (int kt = 0; kt < 4; ++kt)
                    acc[kt][ds] = __builtin_amdgcn_mfma_f32_16x16x32_bf16(afr[kt], bfr, acc[kt][ds], 0, 0, 0);
            }
        }
    }
#undef LOADCH

    float* Pb = P + (size_t)ms * (KC * DIM) + d0;
#pragma unroll
    for (int kt = 0; kt < 4; ++kt)
#pragma unroll
        for (int ds = 0; ds < 2; ++ds) {
            int d = wave * 32 + ds * 16 + l15;
#pragma unroll
            for (int r4 = 0; r4 < 4; ++r4) {
                int k = kt * 16 + lhi * 4 + r4;
                Pb[(size_t)k * DIM + d] = acc[kt][ds][r4];
            }
        }
}

// ---------------- K4: partial-reduce + mass-reduce + finalize centers -------------
__global__ __launch_bounds__(256) void k_final(const float* __restrict__ P,
                                               const float* __restrict__ PSM,
                                               const float* __restrict__ cn,
                                               float* __restrict__ outC) {
    int k = blockIdx.x, tid = threadIdx.x;
    __shared__ float red[4];

    float msum = 0.f;
    for (int p = tid; p < SINK_BLOCKS; p += 256) msum += PSM[(size_t)p * KC + k];
    for (int o = 32; o; o >>= 1) msum += __shfl_xor(msum, o);
    if ((tid & 63) == 0) red[tid >> 6] = msum;
    __syncthreads();
    float mk = fmaxf(red[0] + red[1] + red[2] + red[3], 1e-6f);
    __syncthreads();

    float w[3];
#pragma unroll
    for (int g = 0; g < 3; ++g) {
        int d = tid + g * 256;
        const float* pp = P + (size_t)k * DIM + d;
        float s0 = 0.f, s1 = 0.f, s2 = 0.f, s3 = 0.f;
        size_t stride = (size_t)KC * DIM;
#pragma unroll 4
        for (int msg = 0; msg < MSEG; msg += 4) {
            s0 += pp[(size_t)msg * stride];
            s1 += pp[(size_t)(msg + 1) * stride];
            s2 += pp[(size_t)(msg + 2) * stride];
            s3 += pp[(size_t)(msg + 3) * stride];
        }
        w[g] = ((s0 + s1) + (s2 + s3)) / mk;
    }

    float ss = w[0] * w[0] + w[1] * w[1] + w[2] * w[2];
    for (int o = 32; o; o >>= 1) ss += __shfl_xor(ss, o);
    if ((tid & 63) == 0) red[tid >> 6] = ss;
    __syncthreads();
    ss = red[0] + red[1] + red[2] + red[3];
    float n1 = fmaxf(sqrtf(ss), 1e-12f);
    __syncthreads();

    float u0 = 0.99f * cn[k * DIM + tid]       + 0.01f * (w[0] / n1);
    float u1 = 0.99f * cn[k * DIM + tid + 256] + 0.01f * (w[1] / n1);
    float u2 = 0.99f * cn[k * DIM + tid + 512] + 0.01f * (w[2] / n1);
    float ss2 = u0 * u0 + u1 * u1 + u2 * u2;
    for (int o = 32; o; o >>= 1) ss2 += __shfl_xor(ss2, o);
    if ((tid & 63) == 0) red[tid >> 6] = ss2;
    __syncthreads();
    ss2 = red[0] + red[1] + red[2] + red[3];
    float n2 = fmaxf(sqrtf(ss2), 1e-12f);

    outC[k * DIM + tid]       = u0 / n2;
    outC[k * DIM + tid + 256] = u1 / n2;
    outC[k * DIM + tid + 512] = u2 / n2;
}

extern "C" void kernel_launch(void* const* d_in, const int* in_sizes, int n_in,
                              void* d_out, int out_size, void* d_ws, size_t ws_size,
                              hipStream_t stream) {
    const float* F = (const float*)d_in[0];        // [65536][768]
    const float* centers = (const float*)d_in[1];  // [64][768]
    float* out = (float*)d_out;
    float* A = out;                                 // assignments [65536][64]
    float* outC = out + (size_t)M_TOTAL * KC;       // updated centers [64][768]

    float* w = (float*)d_ws;                        // ws = 768 MiB
    float* cn   = w;                                // 49152
    short* cnbf = (short*)(w + 49152);              // 24576 float slots
    float* R0   = w + 73728;                        // 64
    float* R1   = w + 73792;                        // 64
    float* R2   = w + 73856;                        // 64
    float* invn = w + 74048;                        // 65536
    float* cbuf = w + 139584;                       // 65536
    float* E    = w + 205120;                       // 4194304 (pre-swizzled layout)
    short* Qbf  = (short*)(w + 4399424);            // 2097152 float slots (8 MiB)
    float* PS0  = w + 6496576;                      // 1024*64
    float* PS1  = w + 6562112;                      // 512*64
    float* PS2  = w + 6594880;                      // 512*64
    float* PSM  = w + 6627648;                      // 512*64
    float* partial = w + 6660416;                   // MSEG*64*768 = 6291456 (24 MiB)

    k_centers<<<KC, 256, 0, stream>>>(centers, cn, cnbf);
    k_logits<<<LOGITS_BLOCKS, 256, 0, stream>>>(F, cnbf, E, invn, PS0);
    k_redR<0><<<1, 1024, 0, stream>>>(PS0, LOGITS_BLOCKS, nullptr, R0);
    k_sink<0><<<SINK_BLOCKS, 256, 0, stream>>>(E, R0, invn, cbuf, PS1, A, Qbf);
    k_redR<1><<<1, 1024, 0, stream>>>(PS1, SINK_BLOCKS, R0, R1);
    k_sink<1><<<SINK_BLOCKS, 256, 0, stream>>>(E, R1, invn, cbuf, PS2, A, Qbf);
    k_redR<1><<<1, 1024, 0, stream>>>(PS2, SINK_BLOCKS, R1, R2);
    k_sink<2><<<SINK_BLOCKS, 256, 0, stream>>>(E, R2, invn, cbuf, PSM, A, Qbf);

    dim3 wgrid(DIM / DT, MSEG);
    k_weighted<<<wgrid, 256, 0, stream>>>(F, Qbf, partial);
    k_final<<<KC, 256, 0, stream>>>(partial, PSM, cn, outC);
}

// Round 10
// 192.931 us; speedup vs baseline: 1.0361x; 1.0361x over previous
//
#include <hip/hip_runtime.h>
#include <hip/hip_bf16.h>

#define M_TOTAL 65536
#define DIM 768
#define KC 64
#define INV_T 10.0f

// k_weighted tiling
#define DT 128    // d-cols per block
#define MB 64     // m per LDS chunk
#define CH 8      // chunks per block (m-range 512)
#define MSEG 128  // m-segments (partials)

#define LOGITS_BLOCKS (M_TOTAL / 64)   // 1024 (64 rows per block)
#define SROWS 128
#define SINK_BLOCKS (M_TOTAL / SROWS)  // 512

typedef __attribute__((ext_vector_type(4))) float f32x4;
typedef __attribute__((ext_vector_type(8))) short bf16x8;
typedef __attribute__((ext_vector_type(4))) unsigned short u16x4;

__device__ __forceinline__ short f2bf(float f) {
    __hip_bfloat16 h = __float2bfloat16(f);
    union { __hip_bfloat16 h; short s; } u; u.h = h;
    return u.s;
}

// ---------------- K0: normalize centers -> cn (fp32) + cnbf (bf16) ----------------
__global__ __launch_bounds__(256) void k_centers(const float* __restrict__ centers,
                                                 float* __restrict__ cn,
                                                 short* __restrict__ cnbf) {
    int k = blockIdx.x, tid = threadIdx.x;
    float ss = 0.f;
    for (int i = tid; i < DIM; i += 256) { float v = centers[k * DIM + i]; ss += v * v; }
    __shared__ float red[4];
    for (int o = 32; o; o >>= 1) ss += __shfl_xor(ss, o);
    if ((tid & 63) == 0) red[tid >> 6] = ss;
    __syncthreads();
    ss = red[0] + red[1] + red[2] + red[3];
    float inv = 1.0f / fmaxf(sqrtf(ss), 1e-12f);
    for (int i = tid; i < DIM; i += 256) {
        float v = centers[k * DIM + i] * inv;
        cn[k * DIM + i] = v;
        cnbf[k * DIM + i] = f2bf(v);
    }
}

// ---------------- K1: logits GEMM (R8 form: 2-buffer global_load_lds staged) ------
// R9 lesson: 3-buffer counted-vmcnt pipeline LOST (49KB LDS -> 3 blk/CU); this 34KB
// 2-buffer form keeps 4 blk/CU and TLP hides the barrier drain. E stored pre-swizzled
// E[m][c] = E_true[m][c ^ ((m&15)<<2)] for the shuffle-free sinks.
__global__ __launch_bounds__(256) void k_logits(const float* __restrict__ F,
                                                const short* __restrict__ cnbf,
                                                float* __restrict__ E,
                                                float* __restrict__ invn,
                                                float* __restrict__ PS0) {
    __shared__ float fbuf[2][4096];  // [row 0..63][col 0..63], swizzled-by-source
    __shared__ float bsr[4][KC];
    int tid = threadIdx.x;
    int wave = tid >> 6, lane = tid & 63;
    int l15 = lane & 15, lhi = lane >> 4;
    int rowbase = blockIdx.x * 64;

    int srow = tid >> 4;       // staging row 0..15 (+16 per issue)
    int c4 = (tid & 15) * 4;   // staging col group

    f32x4 acc[4];
#pragma unroll
    for (int n = 0; n < 4; ++n) acc[n] = (f32x4){0.f, 0.f, 0.f, 0.f};
    float ss = 0.f;

    auto stage = [&](int t, int b) {
#pragma unroll
        for (int i = 0; i < 4; ++i) {
            int row = i * 16 + srow;
            const float* src = F + (size_t)(rowbase + row) * DIM + t * 64 + (c4 ^ ((row & 7) << 2));
            float* dst = &fbuf[b][i * 1024 + wave * 256];  // wave-uniform; HW adds lane*16B
            __builtin_amdgcn_global_load_lds((const __attribute__((address_space(1))) void*)src,
                                             (__attribute__((address_space(3))) void*)dst, 16, 0, 0);
        }
    };

    stage(0, 0);
    __syncthreads();

    int myrow = wave * 16 + l15;
    int swz = (l15 & 7) << 2;
    const short* Bb = cnbf + (size_t)l15 * DIM + lhi * 8;

    for (int t = 0; t < 12; ++t) {
        int cur = t & 1;
        if (t < 11) stage(t + 1, cur ^ 1);  // in flight during compute below
        const float* cb = fbuf[cur] + myrow * 64;
#pragma unroll
        for (int kk = 0; kk < 64; kk += 32) {
            int c0s = (kk + lhi * 8) ^ swz;
            f32x4 fa = *(const f32x4*)(cb + c0s);
            f32x4 fb2 = *(const f32x4*)(cb + (c0s ^ 4));
            ss += fa[0] * fa[0] + fa[1] * fa[1] + fa[2] * fa[2] + fa[3] * fa[3]
                + fb2[0] * fb2[0] + fb2[1] * fb2[1] + fb2[2] * fb2[2] + fb2[3] * fb2[3];
            bf16x8 af;
            af[0] = f2bf(fa[0]); af[1] = f2bf(fa[1]); af[2] = f2bf(fa[2]); af[3] = f2bf(fa[3]);
            af[4] = f2bf(fb2[0]); af[5] = f2bf(fb2[1]); af[6] = f2bf(fb2[2]); af[7] = f2bf(fb2[3]);
#pragma unroll
            for (int n = 0; n < 4; ++n) {
                bf16x8 b = *(const bf16x8*)(Bb + (size_t)n * 16 * DIM + t * 64 + kk);
                acc[n] = __builtin_amdgcn_mfma_f32_16x16x32_bf16(af, b, acc[n], 0, 0, 0);
            }
        }
        __syncthreads();
    }

    // ---- per-wave epilogue ----
    ss += __shfl_xor(ss, 16);
    ss += __shfl_xor(ss, 32);
    float inv = 1.0f / fmaxf(sqrtf(ss), 1e-12f);
    int growbase = rowbase + wave * 16;
    if (lane < 16) invn[growbase + lane] = inv;

    float sc[4];
#pragma unroll
    for (int j = 0; j < 4; ++j) sc[j] = __shfl(inv, lhi * 4 + j) * INV_T;

    float colp[4] = {0.f, 0.f, 0.f, 0.f};
#pragma unroll
    for (int n = 0; n < 4; ++n) {
#pragma unroll
        for (int j = 0; j < 4; ++j) {
            float e = expf(acc[n][j] * sc[j]);
            int row = lhi * 4 + j;  // row & 15
            E[(size_t)(growbase + row) * KC + ((n * 16 + l15) ^ (row << 2))] = e;
            colp[n] += e;
        }
    }
#pragma unroll
    for (int n = 0; n < 4; ++n) {
        colp[n] += __shfl_xor(colp[n], 16);
        colp[n] += __shfl_xor(colp[n], 32);
    }
    if (lane < 16) {
#pragma unroll
        for (int n = 0; n < 4; ++n) bsr[wave][n * 16 + lane] = colp[n];
    }
    __syncthreads();
    if (tid < KC) PS0[(size_t)blockIdx.x * KC + tid] =
        bsr[0][tid] + bsr[1][tid] + bsr[2][tid] + bsr[3][tid];
}

// ---------------- P: sink pass with fused R-chain preamble ------------------------
// Preamble: every block reduces PSprev -> R redundantly (deterministic, identical),
// writes R to global (same-value race, benign) for the next pass. No fences, no
// k_redR launches. Phases: stage E tile -> row sums with R fused via swizzle algebra
// (stored group j^sw == true-k group j -> wave-uniform R4[j] broadcast) -> col step.
template <int MODE>
__global__ __launch_bounds__(256) void k_sink(const float* __restrict__ E,
                                              const float* __restrict__ Rprev,
                                              const float* __restrict__ PSprev,
                                              const float* __restrict__ invn,
                                              float* __restrict__ c,
                                              float* __restrict__ PS,
                                              float* __restrict__ Rout,
                                              float* __restrict__ Aout,
                                              short* __restrict__ Qbf) {
    __shared__ float tile[SROWS * KC];  // 32 KiB
    __shared__ float sbuf[SROWS];
    __shared__ float Rlds[KC];
    __shared__ float bacc[4][KC];
    int tid = threadIdx.x, lane = tid & 63, wave = tid >> 6;
    int m0 = blockIdx.x * SROWS;

    // issue E staging FIRST (latency hides under the preamble)
#pragma unroll
    for (int i = 0; i < 8; ++i) {
        const float* src = E + (size_t)(m0 + i * 16 + wave * 4 + (lane >> 4)) * KC + (lane & 15) * 4;
        float* dst = tile + (i * 16 + wave * 4) * KC;
        __builtin_amdgcn_global_load_lds((const __attribute__((address_space(1))) void*)src,
                                         (__attribute__((address_space(3))) void*)dst, 16, 0, 0);
    }

    // ---- preamble: PSprev -> R (redundant per block) ----
    {
        constexpr int NB = (MODE == 0) ? LOGITS_BLOCKS : SINK_BLOCKS;
        int k = tid & 63, g = tid >> 6;
        float s = 0.f;
#pragma unroll 8
        for (int p = g; p < NB; p += 4) s += PSprev[(size_t)p * KC + k];
        bacc[g][k] = s;
        __syncthreads();
        if (tid < KC) {
            float sk = bacc[0][k] + bacc[1][k] + bacc[2][k] + bacc[3][k];
            float r;
            if (MODE == 0) {
                float tot = sk;
                for (int o = 32; o; o >>= 1) tot += __shfl_xor(tot, o);
                float S = fmaxf(tot, 1e-12f);
                r = (1.0f / S) / (fmaxf(sk / S, 1e-12f) * 64.0f);
            } else {
                float rp = Rprev[k];
                r = rp / (fmaxf(rp * sk, 1e-12f) * 64.0f);
            }
            Rlds[k] = r;
            if (MODE != 2) Rout[k] = r;  // all blocks write identical values
        }
    }
    __syncthreads();  // Rlds visible; stage drained (vmcnt 0 at barrier)

    // ---- phase 2: row sums of E_true*R (thread-per-row; R4[j] is wave-uniform) ----
    if (tid < SROWS) {
        const float* rp = tile + tid * KC;
        const f32x4* R4 = (const f32x4*)Rlds;
        int sw = tid & 15;
        f32x4 a = {0.f, 0.f, 0.f, 0.f};
#pragma unroll
        for (int j = 0; j < 16; ++j)
            a += *(const f32x4*)(rp + ((j ^ sw) << 2)) * R4[j];
        sbuf[tid] = a[0] + a[1] + a[2] + a[3];
    }
    __syncthreads();

    // ---- phase 3: lane = k; 32 rows per wave ----
    float Rl = Rlds[lane];
    float wacc = 0.f;
    int rbase = wave * 32;
#pragma unroll 4
    for (int r = 0; r < 32; ++r) {
        int rr = rbase + r;
        int m = m0 + rr;
        float e = tile[rr * KC + (lane ^ ((rr & 15) << 2))];  // raw E_true[m][lane]
        float s = sbuf[rr];
        float cold = (MODE == 0) ? 1.0f : c[m];
        float cnew = cold / (fmaxf(cold * s, 1e-12f) * 65536.0f);
        if (MODE == 2) {
            float a = e * Rl * cnew * 65536.0f;
            size_t idx = (size_t)m * KC + lane;
            Aout[idx] = a;
            Qbf[idx] = f2bf(a * invn[m]);
            wacc += a;
        } else {
            if (lane == 0) c[m] = cnew;
            wacc += e * cnew;  // = sum_m E*c directly (no /R needed)
        }
    }
    bacc[wave][lane] = wacc;
    __syncthreads();
    if (tid < KC) PS[(size_t)blockIdx.x * KC + tid] =
        bacc[0][tid] + bacc[1][tid] + bacc[2][tid] + bacc[3][tid];
}

// ---------------- K3: weighted centers — bf16 MFMA GEMM, prefetched ---------------
__global__ __launch_bounds__(256) void k_weighted(const float* __restrict__ F,
                                                  const short* __restrict__ Qbf,
                                                  float* __restrict__ P) {
    __shared__ short ldsF[DT * MB];  // [d][m] swizzled, 16 KiB
    __shared__ short ldsQ[KC * MB];  // [k][m] swizzled, 8 KiB
    int tid = threadIdx.x;
    int dt = blockIdx.x;  // 0..5
    int ms = blockIdx.y;  // 0..MSEG-1
    int wave = tid >> 6, lane = tid & 63;
    int l15 = lane & 15, lhi = lane >> 4;

    int m0 = ms * (MB * CH);
    int d0 = dt * DT;

    f32x4 acc[4][2];
#pragma unroll
    for (int kt = 0; kt < 4; ++kt)
#pragma unroll
        for (int ds = 0; ds < 2; ++ds) acc[kt][ds] = (f32x4){0.f, 0.f, 0.f, 0.f};

    int f_dq = (tid & 31) * 4;        // d 0..124 (float4 loads)
    int f_m8 = (tid >> 5) * 8;        // m 0..56
    int q_kq = (tid & 15) * 4;        // k 0..60   (threads <128)
    int q_m8 = ((tid >> 4) & 7) * 8;  // m 0..56

    float4 rf[8];
    u16x4 q[8];
#define LOADCH(mb_)                                                                       \
    do {                                                                                  \
        _Pragma("unroll") for (int j = 0; j < 8; ++j)                                     \
            rf[j] = *(const float4*)(F + (size_t)((mb_) + f_m8 + j) * DIM + d0 + f_dq);   \
        if (tid < 128) {                                                                  \
            _Pragma("unroll") for (int j = 0; j < 8; ++j)                                 \
                q[j] = *(const u16x4*)(Qbf + (size_t)((mb_) + q_m8 + j) * KC + q_kq);     \
        }                                                                                 \
    } while (0)

    LOADCH(m0);
    for (int ch = 0; ch < CH; ++ch) {
        __syncthreads();  // previous chunk's LDS reads done before overwrite
#pragma unroll
        for (int i = 0; i < 4; ++i) {
            int d = f_dq + i;
            uint4 w;
            w.x = (unsigned)(unsigned short)f2bf(rf[0][i]) | ((unsigned)(unsigned short)f2bf(rf[1][i]) << 16);
            w.y = (unsigned)(unsigned short)f2bf(rf[2][i]) | ((unsigned)(unsigned short)f2bf(rf[3][i]) << 16);
            w.z = (unsigned)(unsigned short)f2bf(rf[4][i]) | ((unsigned)(unsigned short)f2bf(rf[5][i]) << 16);
            w.w = (unsigned)(unsigned short)f2bf(rf[6][i]) | ((unsigned)(unsigned short)f2bf(rf[7][i]) << 16);
            int byte = (d * (MB * 2) + f_m8 * 2) ^ ((d & 7) << 4);
            *(uint4*)((char*)ldsF + byte) = w;
        }
        if (tid < 128) {
#pragma unroll
            for (int i = 0; i < 4; ++i) {
                int k = q_kq + i;
                uint4 w;
                w.x = (unsigned)q[0][i] | ((unsigned)q[1][i] << 16);
                w.y = (unsigned)q[2][i] | ((unsigned)q[3][i] << 16);
                w.z = (unsigned)q[4][i] | ((unsigned)q[5][i] << 16);
                w.w = (unsigned)q[6][i] | ((unsigned)q[7][i] << 16);
                int byte = (k * (MB * 2) + q_m8 * 2) ^ ((k & 7) << 4);
                *(uint4*)((char*)ldsQ + byte) = w;
            }
        }
        __syncthreads();
        if (ch + 1 < CH) LOADCH(m0 + (ch + 1) * MB);  // prefetch overlaps MFMA below
#pragma unroll
        for (int h = 0; h < 2; ++h) {
            bf16x8 afr[4];
#pragma unroll
            for (int kt = 0; kt < 4; ++kt) {
                int k = kt * 16 + l15;
                int byte = (k * (MB * 2) + (h * 32 + lhi * 8) * 2) ^ ((k & 7) << 4);
                afr[kt] = *(bf16x8*)((char*)ldsQ + byte);
            }
#pragma unroll
            for (int ds = 0; ds < 2; ++ds) {
                int d = wave * 32 + ds * 16 + l15;
                int byte = (d * (MB * 2) + (h * 32 + lhi * 8) * 2) ^ ((d & 7) << 4);
                bf16x8 bfr = *(bf16x8*)((char*)ldsF + byte);
#pragma unroll
                for (int kt = 0; kt < 4; ++kt)
                    acc[kt][ds] = __builtin_amdgcn_mfma_f32_16x16x32_bf16(afr[kt], bfr, acc[kt][ds], 0, 0, 0);
            }
        }
    }
#undef LOADCH

    float* Pb = P + (size_t)ms * (KC * DIM) + d0;
#pragma unroll
    for (int kt = 0; kt < 4; ++kt)
#pragma unroll
        for (int ds = 0; ds < 2; ++ds) {
            int d = wave * 32 + ds * 16 + l15;
#pragma unroll
            for (int r4 = 0; r4 < 4; ++r4) {
                int k = kt * 16 + lhi * 4 + r4;
                Pb[(size_t)k * DIM + d] = acc[kt][ds][r4];
            }
        }
}

// ---------------- K4: partial-reduce + mass-reduce + finalize centers -------------
__global__ __launch_bounds__(256) void k_final(const float* __restrict__ P,
                                               const float* __restrict__ PSM,
                                               const float* __restrict__ cn,
                                               float* __restrict__ outC) {
    int k = blockIdx.x, tid = threadIdx.x;
    __shared__ float red[4];

    float msum = 0.f;
    for (int p = tid; p < SINK_BLOCKS; p += 256) msum += PSM[(size_t)p * KC + k];
    for (int o = 32; o; o >>= 1) msum += __shfl_xor(msum, o);
    if ((tid & 63) == 0) red[tid >> 6] = msum;
    __syncthreads();
    float mk = fmaxf(red[0] + red[1] + red[2] + red[3], 1e-6f);
    __syncthreads();

    float w[3];
#pragma unroll
    for (int g = 0; g < 3; ++g) {
        int d = tid + g * 256;
        const float* pp = P + (size_t)k * DIM + d;
        float s0 = 0.f, s1 = 0.f, s2 = 0.f, s3 = 0.f;
        size_t stride = (size_t)KC * DIM;
#pragma unroll 4
        for (int msg = 0; msg < MSEG; msg += 4) {
            s0 += pp[(size_t)msg * stride];
            s1 += pp[(size_t)(msg + 1) * stride];
            s2 += pp[(size_t)(msg + 2) * stride];
            s3 += pp[(size_t)(msg + 3) * stride];
        }
        w[g] = ((s0 + s1) + (s2 + s3)) / mk;
    }

    float ss = w[0] * w[0] + w[1] * w[1] + w[2] * w[2];
    for (int o = 32; o; o >>= 1) ss += __shfl_xor(ss, o);
    if ((tid & 63) == 0) red[tid >> 6] = ss;
    __syncthreads();
    ss = red[0] + red[1] + red[2] + red[3];
    float n1 = fmaxf(sqrtf(ss), 1e-12f);
    __syncthreads();

    float u0 = 0.99f * cn[k * DIM + tid]       + 0.01f * (w[0] / n1);
    float u1 = 0.99f * cn[k * DIM + tid + 256] + 0.01f * (w[1] / n1);
    float u2 = 0.99f * cn[k * DIM + tid + 512] + 0.01f * (w[2] / n1);
    float ss2 = u0 * u0 + u1 * u1 + u2 * u2;
    for (int o = 32; o; o >>= 1) ss2 += __shfl_xor(ss2, o);
    if ((tid & 63) == 0) red[tid >> 6] = ss2;
    __syncthreads();
    ss2 = red[0] + red[1] + red[2] + red[3];
    float n2 = fmaxf(sqrtf(ss2), 1e-12f);

    outC[k * DIM + tid]       = u0 / n2;
    outC[k * DIM + tid + 256] = u1 / n2;
    outC[k * DIM + tid + 512] = u2 / n2;
}

extern "C" void kernel_launch(void* const* d_in, const int* in_sizes, int n_in,
                              void* d_out, int out_size, void* d_ws, size_t ws_size,
                              hipStream_t stream) {
    const float* F = (const float*)d_in[0];        // [65536][768]
    const float* centers = (const float*)d_in[1];  // [64][768]
    float* out = (float*)d_out;
    float* A = out;                                 // assignments [65536][64]
    float* outC = out + (size_t)M_TOTAL * KC;       // updated centers [64][768]

    float* w = (float*)d_ws;                        // ws = 768 MiB
    float* cn   = w;                                // 49152
    short* cnbf = (short*)(w + 49152);              // 24576 float slots
    float* R0   = w + 73728;                        // 64
    float* R1   = w + 73792;                        // 64
    float* invn = w + 74048;                        // 65536
    float* cbuf = w + 139584;                       // 65536
    float* E    = w + 205120;                       // 4194304 (pre-swizzled layout)
    short* Qbf  = (short*)(w + 4399424);            // 2097152 float slots (8 MiB)
    float* PS0  = w + 6496576;                      // 1024*64
    float* PS1  = w + 6562112;                      // 512*64
    float* PS2  = w + 6594880;                      // 512*64
    float* PSM  = w + 6627648;                      // 512*64
    float* partial = w + 6660416;                   // MSEG*64*768 = 6291456 (24 MiB)

    k_centers<<<KC, 256, 0, stream>>>(centers, cn, cnbf);
    k_logits<<<LOGITS_BLOCKS, 256, 0, stream>>>(F, cnbf, E, invn, PS0);
    k_sink<0><<<SINK_BLOCKS, 256, 0, stream>>>(E, nullptr, PS0, invn, cbuf, PS1, R0, A, Qbf);
    k_sink<1><<<SINK_BLOCKS, 256, 0, stream>>>(E, R0, PS1, invn, cbuf, PS2, R1, A, Qbf);
    k_sink<2><<<SINK_BLOCKS, 256, 0, stream>>>(E, R1, PS2, invn, cbuf, PSM, nullptr, A, Qbf);

    dim3 wgrid(DIM / DT, MSEG);
    k_weighted<<<wgrid, 256, 0, stream>>>(F, Qbf, partial);
    k_final<<<KC, 256, 0, stream>>>(partial, PSM, cn, outC);
}

// Round 11
// 181.401 us; speedup vs baseline: 1.1019x; 1.0636x over previous
//
#include <hip/hip_runtime.h>
#include <hip/hip_bf16.h>

#define M_TOTAL 65536
#define DIM 768
#define KC 64
#define INV_T 10.0f

// k_weighted tiling
#define DT 128    // d-cols per block
#define MB 64     // m per LDS chunk
#define CH 8      // chunks per block (m-range 512)
#define MSEG 128  // m-segments (partials)

#define LOGITS_BLOCKS (M_TOTAL / 64)   // 1024 (64 rows per block)
#define SROWS 128
#define SINK_BLOCKS (M_TOTAL / SROWS)  // 512

typedef __attribute__((ext_vector_type(4))) float f32x4;
typedef __attribute__((ext_vector_type(8))) short bf16x8;
typedef __attribute__((ext_vector_type(4))) unsigned short u16x4;

__device__ __forceinline__ short f2bf(float f) {
    __hip_bfloat16 h = __float2bfloat16(f);
    union { __hip_bfloat16 h; short s; } u; u.h = h;
    return u.s;
}

// ---------------- K0: normalize centers -> cn (fp32) + cnbf (bf16) ----------------
__global__ __launch_bounds__(256) void k_centers(const float* __restrict__ centers,
                                                 float* __restrict__ cn,
                                                 short* __restrict__ cnbf) {
    int k = blockIdx.x, tid = threadIdx.x;
    float ss = 0.f;
    for (int i = tid; i < DIM; i += 256) { float v = centers[k * DIM + i]; ss += v * v; }
    __shared__ float red[4];
    for (int o = 32; o; o >>= 1) ss += __shfl_xor(ss, o);
    if ((tid & 63) == 0) red[tid >> 6] = ss;
    __syncthreads();
    ss = red[0] + red[1] + red[2] + red[3];
    float inv = 1.0f / fmaxf(sqrtf(ss), 1e-12f);
    for (int i = tid; i < DIM; i += 256) {
        float v = centers[k * DIM + i] * inv;
        cn[k * DIM + i] = v;
        cnbf[k * DIM + i] = f2bf(v);
    }
}

// ---------------- K1: logits GEMM — wave-autonomous, barrier-free pipeline --------
// Each wave owns 16 rows and stages its OWN 16x64 f32 tile via 4 wave-uniform
// global_load_lds issues (dst lane-deposit = row (lane>>4), col (lane&15) — linear).
// 3 wave-private buffers; per-iter: B(t) loads, S(t+2) stage, s_waitcnt vmcnt(4)
// (retires own S(t)+B(t), keeps S(t+2) in flight). NO __syncthreads in the K-loop —
// 12 independent wave pipelines per CU instead of 4 barrier convoys (R10 lesson).
// E stored pre-swizzled: E[m][c] = E_true[m][c ^ ((m&15)<<2)].
__global__ __launch_bounds__(256) void k_logits(const float* __restrict__ F,
                                                const short* __restrict__ cnbf,
                                                float* __restrict__ E,
                                                float* __restrict__ invn,
                                                float* __restrict__ PS0) {
    __shared__ float fbuf[3][4][1024];  // [buf][wave][16 rows x 64 cols], 48 KiB
    __shared__ float bsr[4][KC];
    int tid = threadIdx.x;
    int wave = tid >> 6, lane = tid & 63;
    int l15 = lane & 15, lhi = lane >> 4;
    int rowbase = blockIdx.x * 64;

    // wave-private staging: issue i covers local rows i*4..i*4+3
    int srow_l = lane >> 4;          // row within 4-row group
    int c4 = lane & 15;              // col granule (16B)

#define STAGE(t_, b_)                                                                     \
    do {                                                                                  \
        _Pragma("unroll") for (int i_ = 0; i_ < 4; ++i_) {                                \
            int r_ = i_ * 4 + srow_l;  /* local row 0..15 */                              \
            const float* src_ = F + (size_t)(rowbase + wave * 16 + r_) * DIM + (t_) * 64  \
                                + (((c4 ^ (r_ & 7)) << 2));                               \
            float* dst_ = &fbuf[b_][wave][i_ * 256];                                      \
            __builtin_amdgcn_global_load_lds(                                             \
                (const __attribute__((address_space(1))) void*)src_,                      \
                (__attribute__((address_space(3))) void*)dst_, 16, 0, 0);                 \
        }                                                                                 \
    } while (0)

    STAGE(0, 0);
    STAGE(1, 1);

    f32x4 acc[4];
#pragma unroll
    for (int n = 0; n < 4; ++n) acc[n] = (f32x4){0.f, 0.f, 0.f, 0.f};
    float ss = 0.f;

    const short* Bb = cnbf + (size_t)l15 * DIM + lhi * 8;
    int swz = (l15 & 7) << 2;

#pragma unroll
    for (int t = 0; t < 12; ++t) {
        bf16x8 b[8];
#pragma unroll
        for (int n = 0; n < 4; ++n) {
            b[n * 2]     = *(const bf16x8*)(Bb + (size_t)n * 16 * DIM + t * 64);
            b[n * 2 + 1] = *(const bf16x8*)(Bb + (size_t)n * 16 * DIM + t * 64 + 32);
        }
        if (t + 2 < 12) {
            STAGE(t + 2, (t + 2) % 3);
            asm volatile("s_waitcnt vmcnt(4)" ::: "memory");  // S(t)+B(t) done; S(t+2) in flight
        } else {
            asm volatile("s_waitcnt vmcnt(0)" ::: "memory");
        }
        __builtin_amdgcn_sched_barrier(0);
        const float* cb = &fbuf[t % 3][wave][l15 * 64];
#pragma unroll
        for (int kk = 0; kk < 2; ++kk) {
            int c0s = (kk * 32 + lhi * 8) ^ swz;
            f32x4 fa = *(const f32x4*)(cb + c0s);
            f32x4 fb2 = *(const f32x4*)(cb + (c0s ^ 4));
            ss += fa[0] * fa[0] + fa[1] * fa[1] + fa[2] * fa[2] + fa[3] * fa[3]
                + fb2[0] * fb2[0] + fb2[1] * fb2[1] + fb2[2] * fb2[2] + fb2[3] * fb2[3];
            bf16x8 af;
            af[0] = f2bf(fa[0]); af[1] = f2bf(fa[1]); af[2] = f2bf(fa[2]); af[3] = f2bf(fa[3]);
            af[4] = f2bf(fb2[0]); af[5] = f2bf(fb2[1]); af[6] = f2bf(fb2[2]); af[7] = f2bf(fb2[3]);
#pragma unroll
            for (int n = 0; n < 4; ++n)
                acc[n] = __builtin_amdgcn_mfma_f32_16x16x32_bf16(af, b[n * 2 + kk], acc[n], 0, 0, 0);
        }
    }
#undef STAGE

    // ---- per-wave epilogue ----
    ss += __shfl_xor(ss, 16);
    ss += __shfl_xor(ss, 32);
    float inv = 1.0f / fmaxf(sqrtf(ss), 1e-12f);
    int growbase = rowbase + wave * 16;
    if (lane < 16) invn[growbase + lane] = inv;

    float sc[4];
#pragma unroll
    for (int j = 0; j < 4; ++j) sc[j] = __shfl(inv, lhi * 4 + j) * INV_T;

    float colp[4] = {0.f, 0.f, 0.f, 0.f};
#pragma unroll
    for (int n = 0; n < 4; ++n) {
#pragma unroll
        for (int j = 0; j < 4; ++j) {
            float e = expf(acc[n][j] * sc[j]);
            int row = lhi * 4 + j;  // row & 15
            E[(size_t)(growbase + row) * KC + ((n * 16 + l15) ^ (row << 2))] = e;
            colp[n] += e;
        }
    }
#pragma unroll
    for (int n = 0; n < 4; ++n) {
        colp[n] += __shfl_xor(colp[n], 16);
        colp[n] += __shfl_xor(colp[n], 32);
    }
    if (lane < 16) {
#pragma unroll
        for (int n = 0; n < 4; ++n) bsr[wave][n * 16 + lane] = colp[n];
    }
    __syncthreads();
    if (tid < KC) PS0[(size_t)blockIdx.x * KC + tid] =
        bsr[0][tid] + bsr[1][tid] + bsr[2][tid] + bsr[3][tid];
}

// ---------------- P: sink pass with fused R-chain preamble ------------------------
template <int MODE>
__global__ __launch_bounds__(256) void k_sink(const float* __restrict__ E,
                                              const float* __restrict__ Rprev,
                                              const float* __restrict__ PSprev,
                                              const float* __restrict__ invn,
                                              float* __restrict__ c,
                                              float* __restrict__ PS,
                                              float* __restrict__ Rout,
                                              float* __restrict__ Aout,
                                              short* __restrict__ Qbf) {
    __shared__ float tile[SROWS * KC];  // 32 KiB
    __shared__ float sbuf[SROWS];
    __shared__ float Rlds[KC];
    __shared__ float bacc[4][KC];
    int tid = threadIdx.x, lane = tid & 63, wave = tid >> 6;
    int m0 = blockIdx.x * SROWS;

    // issue E staging FIRST (latency hides under the preamble)
#pragma unroll
    for (int i = 0; i < 8; ++i) {
        const float* src = E + (size_t)(m0 + i * 16 + wave * 4 + (lane >> 4)) * KC + (lane & 15) * 4;
        float* dst = tile + (i * 16 + wave * 4) * KC;
        __builtin_amdgcn_global_load_lds((const __attribute__((address_space(1))) void*)src,
                                         (__attribute__((address_space(3))) void*)dst, 16, 0, 0);
    }

    // ---- preamble: PSprev -> R (redundant per block) ----
    {
        constexpr int NB = (MODE == 0) ? LOGITS_BLOCKS : SINK_BLOCKS;
        int k = tid & 63, g = tid >> 6;
        float s = 0.f;
#pragma unroll 8
        for (int p = g; p < NB; p += 4) s += PSprev[(size_t)p * KC + k];
        bacc[g][k] = s;
        __syncthreads();
        if (tid < KC) {
            float sk = bacc[0][k] + bacc[1][k] + bacc[2][k] + bacc[3][k];
            float r;
            if (MODE == 0) {
                float tot = sk;
                for (int o = 32; o; o >>= 1) tot += __shfl_xor(tot, o);
                float S = fmaxf(tot, 1e-12f);
                r = (1.0f / S) / (fmaxf(sk / S, 1e-12f) * 64.0f);
            } else {
                float rp = Rprev[k];
                r = rp / (fmaxf(rp * sk, 1e-12f) * 64.0f);
            }
            Rlds[k] = r;
            if (MODE != 2) Rout[k] = r;  // all blocks write identical values
        }
    }
    __syncthreads();  // Rlds visible; stage drained (vmcnt 0 at barrier)

    // ---- phase 2: row sums of E_true*R (thread-per-row; R4[j] is wave-uniform) ----
    if (tid < SROWS) {
        const float* rp = tile + tid * KC;
        const f32x4* R4 = (const f32x4*)Rlds;
        int sw = tid & 15;
        f32x4 a = {0.f, 0.f, 0.f, 0.f};
#pragma unroll
        for (int j = 0; j < 16; ++j)
            a += *(const f32x4*)(rp + ((j ^ sw) << 2)) * R4[j];
        sbuf[tid] = a[0] + a[1] + a[2] + a[3];
    }
    __syncthreads();

    // ---- phase 3: lane = k; 32 rows per wave ----
    float Rl = Rlds[lane];
    float wacc = 0.f;
    int rbase = wave * 32;
#pragma unroll 4
    for (int r = 0; r < 32; ++r) {
        int rr = rbase + r;
        int m = m0 + rr;
        float e = tile[rr * KC + (lane ^ ((rr & 15) << 2))];  // raw E_true[m][lane]
        float s = sbuf[rr];
        float cold = (MODE == 0) ? 1.0f : c[m];
        float cnew = cold / (fmaxf(cold * s, 1e-12f) * 65536.0f);
        if (MODE == 2) {
            float a = e * Rl * cnew * 65536.0f;
            size_t idx = (size_t)m * KC + lane;
            Aout[idx] = a;
            Qbf[idx] = f2bf(a * invn[m]);
            wacc += a;
        } else {
            if (lane == 0) c[m] = cnew;
            wacc += e * cnew;  // = sum_m E*c directly (no /R needed)
        }
    }
    bacc[wave][lane] = wacc;
    __syncthreads();
    if (tid < KC) PS[(size_t)blockIdx.x * KC + tid] =
        bacc[0][tid] + bacc[1][tid] + bacc[2][tid] + bacc[3][tid];
}

// ---------------- K3: weighted centers — bf16 MFMA GEMM, prefetched ---------------
__global__ __launch_bounds__(256) void k_weighted(const float* __restrict__ F,
                                                  const short* __restrict__ Qbf,
                                                  float* __restrict__ P) {
    __shared__ short ldsF[DT * MB];  // [d][m] swizzled, 16 KiB
    __shared__ short ldsQ[KC * MB];  // [k][m] swizzled, 8 KiB
    int tid = threadIdx.x;
    int dt = blockIdx.x;  // 0..5
    int ms = blockIdx.y;  // 0..MSEG-1
    int wave = tid >> 6, lane = tid & 63;
    int l15 = lane & 15, lhi = lane >> 4;

    int m0 = ms * (MB * CH);
    int d0 = dt * DT;

    f32x4 acc[4][2];
#pragma unroll
    for (int kt = 0; kt < 4; ++kt)
#pragma unroll
        for (int ds = 0; ds < 2; ++ds) acc[kt][ds] = (f32x4){0.f, 0.f, 0.f, 0.f};

    int f_dq = (tid & 31) * 4;        // d 0..124 (float4 loads)
    int f_m8 = (tid >> 5) * 8;        // m 0..56
    int q_kq = (tid & 15) * 4;        // k 0..60   (threads <128)
    int q_m8 = ((tid >> 4) & 7) * 8;  // m 0..56

    float4 rf[8];
    u16x4 q[8];
#define LOADCH(mb_)                                                                       \
    do {                                                                                  \
        _Pragma("unroll") for (int j = 0; j < 8; ++j)                                     \
            rf[j] = *(const float4*)(F + (size_t)((mb_) + f_m8 + j) * DIM + d0 + f_dq);   \
        if (tid < 128) {                                                                  \
            _Pragma("unroll") for (int j = 0; j < 8; ++j)                                 \
                q[j] = *(const u16x4*)(Qbf + (size_t)((mb_) + q_m8 + j) * KC + q_kq);     \
        }                                                                                 \
    } while (0)

    LOADCH(m0);
    for (int ch = 0; ch < CH; ++ch) {
        __syncthreads();  // previous chunk's LDS reads done before overwrite
#pragma unroll
        for (int i = 0; i < 4; ++i) {
            int d = f_dq + i;
            uint4 w;
            w.x = (unsigned)(unsigned short)f2bf(rf[0][i]) | ((unsigned)(unsigned short)f2bf(rf[1][i]) << 16);
            w.y = (unsigned)(unsigned short)f2bf(rf[2][i]) | ((unsigned)(unsigned short)f2bf(rf[3][i]) << 16);
            w.z = (unsigned)(unsigned short)f2bf(rf[4][i]) | ((unsigned)(unsigned short)f2bf(rf[5][i]) << 16);
            w.w = (unsigned)(unsigned short)f2bf(rf[6][i]) | ((unsigned)(unsigned short)f2bf(rf[7][i]) << 16);
            int byte = (d * (MB * 2) + f_m8 * 2) ^ ((d & 7) << 4);
            *(uint4*)((char*)ldsF + byte) = w;
        }
        if (tid < 128) {
#pragma unroll
            for (int i = 0; i < 4; ++i) {
                int k = q_kq + i;
                uint4 w;
                w.x = (unsigned)q[0][i] | ((unsigned)q[1][i] << 16);
                w.y = (unsigned)q[2][i] | ((unsigned)q[3][i] << 16);
                w.z = (unsigned)q[4][i] | ((unsigned)q[5][i] << 16);
                w.w = (unsigned)q[6][i] | ((unsigned)q[7][i] << 16);
                int byte = (k * (MB * 2) + q_m8 * 2) ^ ((k & 7) << 4);
                *(uint4*)((char*)ldsQ + byte) = w;
            }
        }
        __syncthreads();
        if (ch + 1 < CH) LOADCH(m0 + (ch + 1) * MB);  // prefetch overlaps MFMA below
#pragma unroll
        for (int h = 0; h < 2; ++h) {
            bf16x8 afr[4];
#pragma unroll
            for (int kt = 0; kt < 4; ++kt) {
                int k = kt * 16 + l15;
                int byte = (k * (MB * 2) + (h * 32 + lhi * 8) * 2) ^ ((k & 7) << 4);
                afr[kt] = *(bf16x8*)((char*)ldsQ + byte);
            }
#pragma unroll
            for (int ds = 0; ds < 2; ++ds) {
                int d = wave * 32 + ds * 16 + l15;
                int byte = (d * (MB * 2) + (h * 32 + lhi * 8) * 2) ^ ((d & 7) << 4);
                bf16x8 bfr = *(bf16x8*)((char*)ldsF + byte);
#pragma unroll
                for (int kt = 0; kt < 4; ++kt)
                    acc[kt][ds] = __builtin_amdgcn_mfma_f32_16x16x32_bf16(afr[kt], bfr, acc[kt][ds], 0, 0, 0);
            }
        }
    }
#undef LOADCH

    float* Pb = P + (size_t)ms * (KC * DIM) + d0;
#pragma unroll
    for (int kt = 0; kt < 4; ++kt)
#pragma unroll
        for (int ds = 0; ds < 2; ++ds) {
            int d = wave * 32 + ds * 16 + l15;
#pragma unroll
            for (int r4 = 0; r4 < 4; ++r4) {
                int k = kt * 16 + lhi * 4 + r4;
                Pb[(size_t)k * DIM + d] = acc[kt][ds][r4];
            }
        }
}

// ---------------- K4: partial-reduce + mass-reduce + finalize centers -------------
__global__ __launch_bounds__(256) void k_final(const float* __restrict__ P,
                                               const float* __restrict__ PSM,
                                               const float* __restrict__ cn,
                                               float* __restrict__ outC) {
    int k = blockIdx.x, tid = threadIdx.x;
    __shared__ float red[4];

    float msum = 0.f;
    for (int p = tid; p < SINK_BLOCKS; p += 256) msum += PSM[(size_t)p * KC + k];
    for (int o = 32; o; o >>= 1) msum += __shfl_xor(msum, o);
    if ((tid & 63) == 0) red[tid >> 6] = msum;
    __syncthreads();
    float mk = fmaxf(red[0] + red[1] + red[2] + red[3], 1e-6f);
    __syncthreads();

    float w[3];
#pragma unroll
    for (int g = 0; g < 3; ++g) {
        int d = tid + g * 256;
        const float* pp = P + (size_t)k * DIM + d;
        float s0 = 0.f, s1 = 0.f, s2 = 0.f, s3 = 0.f;
        size_t stride = (size_t)KC * DIM;
#pragma unroll 4
        for (int msg = 0; msg < MSEG; msg += 4) {
            s0 += pp[(size_t)msg * stride];
            s1 += pp[(size_t)(msg + 1) * stride];
            s2 += pp[(size_t)(msg + 2) * stride];
            s3 += pp[(size_t)(msg + 3) * stride];
        }
        w[g] = ((s0 + s1) + (s2 + s3)) / mk;
    }

    float ss = w[0] * w[0] + w[1] * w[1] + w[2] * w[2];
    for (int o = 32; o; o >>= 1) ss += __shfl_xor(ss, o);
    if ((tid & 63) == 0) red[tid >> 6] = ss;
    __syncthreads();
    ss = red[0] + red[1] + red[2] + red[3];
    float n1 = fmaxf(sqrtf(ss), 1e-12f);
    __syncthreads();

    float u0 = 0.99f * cn[k * DIM + tid]       + 0.01f * (w[0] / n1);
    float u1 = 0.99f * cn[k * DIM + tid + 256] + 0.01f * (w[1] / n1);
    float u2 = 0.99f * cn[k * DIM + tid + 512] + 0.01f * (w[2] / n1);
    float ss2 = u0 * u0 + u1 * u1 + u2 * u2;
    for (int o = 32; o; o >>= 1) ss2 += __shfl_xor(ss2, o);
    if ((tid & 63) == 0) red[tid >> 6] = ss2;
    __syncthreads();
    ss2 = red[0] + red[1] + red[2] + red[3];
    float n2 = fmaxf(sqrtf(ss2), 1e-12f);

    outC[k * DIM + tid]       = u0 / n2;
    outC[k * DIM + tid + 256] = u1 / n2;
    outC[k * DIM + tid + 512] = u2 / n2;
}

extern "C" void kernel_launch(void* const* d_in, const int* in_sizes, int n_in,
                              void* d_out, int out_size, void* d_ws, size_t ws_size,
                              hipStream_t stream) {
    const float* F = (const float*)d_in[0];        // [65536][768]
    const float* centers = (const float*)d_in[1];  // [64][768]
    float* out = (float*)d_out;
    float* A = out;                                 // assignments [65536][64]
    float* outC = out + (size_t)M_TOTAL * KC;       // updated centers [64][768]

    float* w = (float*)d_ws;                        // ws = 768 MiB
    float* cn   = w;                                // 49152
    short* cnbf = (short*)(w + 49152);              // 24576 float slots
    float* R0   = w + 73728;                        // 64
    float* R1   = w + 73792;                        // 64
    float* invn = w + 74048;                        // 65536
    float* cbuf = w + 139584;                       // 65536
    float* E    = w + 205120;                       // 4194304 (pre-swizzled layout)
    short* Qbf  = (short*)(w + 4399424);            // 2097152 float slots (8 MiB)
    float* PS0  = w + 6496576;                      // 1024*64
    float* PS1  = w + 6562112;                      // 512*64
    float* PS2  = w + 6594880;                      // 512*64
    float* PSM  = w + 6627648;                      // 512*64
    float* partial = w + 6660416;                   // MSEG*64*768 = 6291456 (24 MiB)

    k_centers<<<KC, 256, 0, stream>>>(centers, cn, cnbf);
    k_logits<<<LOGITS_BLOCKS, 256, 0, stream>>>(F, cnbf, E, invn, PS0);
    k_sink<0><<<SINK_BLOCKS, 256, 0, stream>>>(E, nullptr, PS0, invn, cbuf, PS1, R0, A, Qbf);
    k_sink<1><<<SINK_BLOCKS, 256, 0, stream>>>(E, R0, PS1, invn, cbuf, PS2, R1, A, Qbf);
    k_sink<2><<<SINK_BLOCKS, 256, 0, stream>>>(E, R1, PS2, invn, cbuf, PSM, nullptr, A, Qbf);

    dim3 wgrid(DIM / DT, MSEG);
    k_weighted<<<wgrid, 256, 0, stream>>>(F, Qbf, partial);
    k_final<<<KC, 256, 0, stream>>>(partial, PSM, cn, outC);
}

// Round 12
// 157.629 us; speedup vs baseline: 1.2681x; 1.1508x over previous
//
#include <hip/hip_runtime.h>
#include <hip/hip_bf16.h>

#define M_TOTAL 65536
#define DIM 768
#define KC 64
#define INV_T 10.0f

// k_weighted tiling
#define DT 128    // d-cols per block
#define MB 64     // m per LDS chunk
#define CH 8      // chunks per block (m-range 512)
#define MSEG 128  // m-segments (partials)

#define LOGITS_BLOCKS (M_TOTAL / 64)   // 1024 (64 rows per block)
#define SROWS 128
#define SINK_BLOCKS (M_TOTAL / SROWS)  // 512
#define PSG_ROWS 64                    // two-level PS: 64 group rows of 64 floats

typedef __attribute__((ext_vector_type(4))) float f32x4;
typedef __attribute__((ext_vector_type(8))) short bf16x8;
typedef __attribute__((ext_vector_type(4))) unsigned short u16x4;

__device__ __forceinline__ short f2bf(float f) {
    __hip_bfloat16 h = __float2bfloat16(f);
    union { __hip_bfloat16 h; short s; } u; u.h = h;
    return u.s;
}

// ---------------- K0: normalize centers -> cn + cnbf; zero PSG --------------------
// PSG = 4 arrays [64][64] contiguous (16384 floats); 64 blocks x 256 thr covers it.
__global__ __launch_bounds__(256) void k_centers(const float* __restrict__ centers,
                                                 float* __restrict__ cn,
                                                 short* __restrict__ cnbf,
                                                 float* __restrict__ psg) {
    int k = blockIdx.x, tid = threadIdx.x;
    psg[k * 256 + tid] = 0.f;  // 64*256 = 16384 = all four PSG arrays
    float ss = 0.f;
    for (int i = tid; i < DIM; i += 256) { float v = centers[k * DIM + i]; ss += v * v; }
    __shared__ float red[4];
    for (int o = 32; o; o >>= 1) ss += __shfl_xor(ss, o);
    if ((tid & 63) == 0) red[tid >> 6] = ss;
    __syncthreads();
    ss = red[0] + red[1] + red[2] + red[3];
    float inv = 1.0f / fmaxf(sqrtf(ss), 1e-12f);
    for (int i = tid; i < DIM; i += 256) {
        float v = centers[k * DIM + i] * inv;
        cn[k * DIM + i] = v;
        cnbf[k * DIM + i] = f2bf(v);
    }
}

// ---------------- K1: logits GEMM — wave-autonomous, barrier-free pipeline --------
// (unchanged from R11 except PS0 -> group-atomic PSG0)
__global__ __launch_bounds__(256) void k_logits(const float* __restrict__ F,
                                                const short* __restrict__ cnbf,
                                                float* __restrict__ E,
                                                float* __restrict__ invn,
                                                float* __restrict__ PSG0) {
    __shared__ float fbuf[3][4][1024];  // [buf][wave][16 rows x 64 cols], 48 KiB
    __shared__ float bsr[4][KC];
    int tid = threadIdx.x;
    int wave = tid >> 6, lane = tid & 63;
    int l15 = lane & 15, lhi = lane >> 4;
    int rowbase = blockIdx.x * 64;

    int srow_l = lane >> 4;          // row within 4-row group
    int c4 = lane & 15;              // col granule (16B)

#define STAGE(t_, b_)                                                                     \
    do {                                                                                  \
        _Pragma("unroll") for (int i_ = 0; i_ < 4; ++i_) {                                \
            int r_ = i_ * 4 + srow_l;  /* local row 0..15 */                              \
            const float* src_ = F + (size_t)(rowbase + wave * 16 + r_) * DIM + (t_) * 64  \
                                + (((c4 ^ (r_ & 7)) << 2));                               \
            float* dst_ = &fbuf[b_][wave][i_ * 256];                                      \
            __builtin_amdgcn_global_load_lds(                                             \
                (const __attribute__((address_space(1))) void*)src_,                      \
                (__attribute__((address_space(3))) void*)dst_, 16, 0, 0);                 \
        }                                                                                 \
    } while (0)

    STAGE(0, 0);
    STAGE(1, 1);

    f32x4 acc[4];
#pragma unroll
    for (int n = 0; n < 4; ++n) acc[n] = (f32x4){0.f, 0.f, 0.f, 0.f};
    float ss = 0.f;

    const short* Bb = cnbf + (size_t)l15 * DIM + lhi * 8;
    int swz = (l15 & 7) << 2;

#pragma unroll
    for (int t = 0; t < 12; ++t) {
        bf16x8 b[8];
#pragma unroll
        for (int n = 0; n < 4; ++n) {
            b[n * 2]     = *(const bf16x8*)(Bb + (size_t)n * 16 * DIM + t * 64);
            b[n * 2 + 1] = *(const bf16x8*)(Bb + (size_t)n * 16 * DIM + t * 64 + 32);
        }
        if (t + 2 < 12) {
            STAGE(t + 2, (t + 2) % 3);
            asm volatile("s_waitcnt vmcnt(4)" ::: "memory");  // S(t)+B(t) done; S(t+2) in flight
        } else {
            asm volatile("s_waitcnt vmcnt(0)" ::: "memory");
        }
        __builtin_amdgcn_sched_barrier(0);
        const float* cb = &fbuf[t % 3][wave][l15 * 64];
#pragma unroll
        for (int kk = 0; kk < 2; ++kk) {
            int c0s = (kk * 32 + lhi * 8) ^ swz;
            f32x4 fa = *(const f32x4*)(cb + c0s);
            f32x4 fb2 = *(const f32x4*)(cb + (c0s ^ 4));
            ss += fa[0] * fa[0] + fa[1] * fa[1] + fa[2] * fa[2] + fa[3] * fa[3]
                + fb2[0] * fb2[0] + fb2[1] * fb2[1] + fb2[2] * fb2[2] + fb2[3] * fb2[3];
            bf16x8 af;
            af[0] = f2bf(fa[0]); af[1] = f2bf(fa[1]); af[2] = f2bf(fa[2]); af[3] = f2bf(fa[3]);
            af[4] = f2bf(fb2[0]); af[5] = f2bf(fb2[1]); af[6] = f2bf(fb2[2]); af[7] = f2bf(fb2[3]);
#pragma unroll
            for (int n = 0; n < 4; ++n)
                acc[n] = __builtin_amdgcn_mfma_f32_16x16x32_bf16(af, b[n * 2 + kk], acc[n], 0, 0, 0);
        }
    }
#undef STAGE

    // ---- per-wave epilogue ----
    ss += __shfl_xor(ss, 16);
    ss += __shfl_xor(ss, 32);
    float inv = 1.0f / fmaxf(sqrtf(ss), 1e-12f);
    int growbase = rowbase + wave * 16;
    if (lane < 16) invn[growbase + lane] = inv;

    float sc[4];
#pragma unroll
    for (int j = 0; j < 4; ++j) sc[j] = __shfl(inv, lhi * 4 + j) * INV_T;

    float colp[4] = {0.f, 0.f, 0.f, 0.f};
#pragma unroll
    for (int n = 0; n < 4; ++n) {
#pragma unroll
        for (int j = 0; j < 4; ++j) {
            float e = expf(acc[n][j] * sc[j]);
            int row = lhi * 4 + j;  // row & 15
            E[(size_t)(growbase + row) * KC + ((n * 16 + l15) ^ (row << 2))] = e;
            colp[n] += e;
        }
    }
#pragma unroll
    for (int n = 0; n < 4; ++n) {
        colp[n] += __shfl_xor(colp[n], 16);
        colp[n] += __shfl_xor(colp[n], 32);
    }
    if (lane < 16) {
#pragma unroll
        for (int n = 0; n < 4; ++n) bsr[wave][n * 16 + lane] = colp[n];
    }
    __syncthreads();
    if (tid < KC)  // group-atomic fold: 16 blocks/group, distinct addr per lane
        atomicAdd(&PSG0[(size_t)(blockIdx.x >> 4) * KC + tid],
                  bsr[0][tid] + bsr[1][tid] + bsr[2][tid] + bsr[3][tid]);
}

// ---------------- P: sink pass with fused R-chain preamble (two-level PS) ---------
// Preamble reads the 16 KB PSGprev [64][64] (vs 128-256 KB per-block arrays in R11).
template <int MODE>
__global__ __launch_bounds__(256) void k_sink(const float* __restrict__ E,
                                              const float* __restrict__ Rprev,
                                              const float* __restrict__ PSGprev,
                                              const float* __restrict__ invn,
                                              float* __restrict__ c,
                                              float* __restrict__ PSGnext,
                                              float* __restrict__ Rout,
                                              float* __restrict__ Aout,
                                              short* __restrict__ Qbf) {
    __shared__ float tile[SROWS * KC];  // 32 KiB
    __shared__ float sbuf[SROWS];
    __shared__ float Rlds[KC];
    __shared__ float bacc[4][KC];
    int tid = threadIdx.x, lane = tid & 63, wave = tid >> 6;
    int m0 = blockIdx.x * SROWS;

    // issue E staging FIRST (latency hides under the preamble)
#pragma unroll
    for (int i = 0; i < 8; ++i) {
        const float* src = E + (size_t)(m0 + i * 16 + wave * 4 + (lane >> 4)) * KC + (lane & 15) * 4;
        float* dst = tile + (i * 16 + wave * 4) * KC;
        __builtin_amdgcn_global_load_lds((const __attribute__((address_space(1))) void*)src,
                                         (__attribute__((address_space(3))) void*)dst, 16, 0, 0);
    }

    // ---- preamble: PSGprev [64][64] -> R (redundant per block, 16 KB) ----
    {
        int k = tid & 63, g = tid >> 6;
        float s = 0.f;
#pragma unroll
        for (int p = 0; p < PSG_ROWS / 4; ++p) s += PSGprev[(size_t)(g + p * 4) * KC + k];
        bacc[g][k] = s;
        __syncthreads();
        if (tid < KC) {
            float sk = bacc[0][k] + bacc[1][k] + bacc[2][k] + bacc[3][k];
            float r;
            if (MODE == 0) {
                float tot = sk;
                for (int o = 32; o; o >>= 1) tot += __shfl_xor(tot, o);
                float S = fmaxf(tot, 1e-12f);
                r = (1.0f / S) / (fmaxf(sk / S, 1e-12f) * 64.0f);
            } else {
                float rp = Rprev[k];
                r = rp / (fmaxf(rp * sk, 1e-12f) * 64.0f);
            }
            Rlds[k] = r;
            if (MODE != 2) Rout[k] = r;  // all blocks write identical values
        }
    }
    __syncthreads();  // Rlds visible; stage drained (vmcnt 0 at barrier)

    // ---- phase 2: row sums of E_true*R (thread-per-row; R4[j] is wave-uniform) ----
    if (tid < SROWS) {
        const float* rp = tile + tid * KC;
        const f32x4* R4 = (const f32x4*)Rlds;
        int sw = tid & 15;
        f32x4 a = {0.f, 0.f, 0.f, 0.f};
#pragma unroll
        for (int j = 0; j < 16; ++j)
            a += *(const f32x4*)(rp + ((j ^ sw) << 2)) * R4[j];
        sbuf[tid] = a[0] + a[1] + a[2] + a[3];
    }
    __syncthreads();

    // ---- phase 3: lane = k; 32 rows per wave ----
    float Rl = Rlds[lane];
    float wacc = 0.f;
    int rbase = wave * 32;
#pragma unroll 4
    for (int r = 0; r < 32; ++r) {
        int rr = rbase + r;
        int m = m0 + rr;
        float e = tile[rr * KC + (lane ^ ((rr & 15) << 2))];  // raw E_true[m][lane]
        float s = sbuf[rr];
        float cold = (MODE == 0) ? 1.0f : c[m];
        float cnew = cold / (fmaxf(cold * s, 1e-12f) * 65536.0f);
        if (MODE == 2) {
            float a = e * Rl * cnew * 65536.0f;
            size_t idx = (size_t)m * KC + lane;
            Aout[idx] = a;
            Qbf[idx] = f2bf(a * invn[m]);
            wacc += a;
        } else {
            if (lane == 0) c[m] = cnew;
            wacc += e * cnew;  // = sum_m E*c directly (no /R needed)
        }
    }
    bacc[wave][lane] = wacc;
    __syncthreads();
    if (tid < KC)  // group-atomic fold: 8 blocks/group
        atomicAdd(&PSGnext[(size_t)(blockIdx.x >> 3) * KC + tid],
                  bacc[0][tid] + bacc[1][tid] + bacc[2][tid] + bacc[3][tid]);
}

// ---------------- K3: weighted centers — bf16 MFMA GEMM, prefetched ---------------
__global__ __launch_bounds__(256) void k_weighted(const float* __restrict__ F,
                                                  const short* __restrict__ Qbf,
                                                  float* __restrict__ P) {
    __shared__ short ldsF[DT * MB];  // [d][m] swizzled, 16 KiB
    __shared__ short ldsQ[KC * MB];  // [k][m] swizzled, 8 KiB
    int tid = threadIdx.x;
    int dt = blockIdx.x;  // 0..5
    int ms = blockIdx.y;  // 0..MSEG-1
    int wave = tid >> 6, lane = tid & 63;
    int l15 = lane & 15, lhi = lane >> 4;

    int m0 = ms * (MB * CH);
    int d0 = dt * DT;

    f32x4 acc[4][2];
#pragma unroll
    for (int kt = 0; kt < 4; ++kt)
#pragma unroll
        for (int ds = 0; ds < 2; ++ds) acc[kt][ds] = (f32x4){0.f, 0.f, 0.f, 0.f};

    int f_dq = (tid & 31) * 4;        // d 0..124 (float4 loads)
    int f_m8 = (tid >> 5) * 8;        // m 0..56
    int q_kq = (tid & 15) * 4;        // k 0..60   (threads <128)
    int q_m8 = ((tid >> 4) & 7) * 8;  // m 0..56

    float4 rf[8];
    u16x4 q[8];
#define LOADCH(mb_)                                                                       \
    do {                                                                                  \
        _Pragma("unroll") for (int j = 0; j < 8; ++j)                                     \
            rf[j] = *(const float4*)(F + (size_t)((mb_) + f_m8 + j) * DIM + d0 + f_dq);   \
        if (tid < 128) {                                                                  \
            _Pragma("unroll") for (int j = 0; j < 8; ++j)                                 \
                q[j] = *(const u16x4*)(Qbf + (size_t)((mb_) + q_m8 + j) * KC + q_kq);     \
        }                                                                                 \
    } while (0)

    LOADCH(m0);
    for (int ch = 0; ch < CH; ++ch) {
        __syncthreads();  // previous chunk's LDS reads done before overwrite
#pragma unroll
        for (int i = 0; i < 4; ++i) {
            int d = f_dq + i;
            uint4 w;
            w.x = (unsigned)(unsigned short)f2bf(rf[0][i]) | ((unsigned)(unsigned short)f2bf(rf[1][i]) << 16);
            w.y = (unsigned)(unsigned short)f2bf(rf[2][i]) | ((unsigned)(unsigned short)f2bf(rf[3][i]) << 16);
            w.z = (unsigned)(unsigned short)f2bf(rf[4][i]) | ((unsigned)(unsigned short)f2bf(rf[5][i]) << 16);
            w.w = (unsigned)(unsigned short)f2bf(rf[6][i]) | ((unsigned)(unsigned short)f2bf(rf[7][i]) << 16);
            int byte = (d * (MB * 2) + f_m8 * 2) ^ ((d & 7) << 4);
            *(uint4*)((char*)ldsF + byte) = w;
        }
        if (tid < 128) {
#pragma unroll
            for (int i = 0; i < 4; ++i) {
                int k = q_kq + i;
                uint4 w;
                w.x = (unsigned)q[0][i] | ((unsigned)q[1][i] << 16);
                w.y = (unsigned)q[2][i] | ((unsigned)q[3][i] << 16);
                w.z = (unsigned)q[4][i] | ((unsigned)q[5][i] << 16);
                w.w = (unsigned)q[6][i] | ((unsigned)q[7][i] << 16);
                int byte = (k * (MB * 2) + q_m8 * 2) ^ ((k & 7) << 4);
                *(uint4*)((char*)ldsQ + byte) = w;
            }
        }
        __syncthreads();
        if (ch + 1 < CH) LOADCH(m0 + (ch + 1) * MB);  // prefetch overlaps MFMA below
#pragma unroll
        for (int h = 0; h < 2; ++h) {
            bf16x8 afr[4];
#pragma unroll
            for (int kt = 0; kt < 4; ++kt) {
                int k = kt * 16 + l15;
                int byte = (k * (MB * 2) + (h * 32 + lhi * 8) * 2) ^ ((k & 7) << 4);
                afr[kt] = *(bf16x8*)((char*)ldsQ + byte);
            }
#pragma unroll
            for (int ds = 0; ds < 2; ++ds) {
                int d = wave * 32 + ds * 16 + l15;
                int byte = (d * (MB * 2) + (h * 32 + lhi * 8) * 2) ^ ((d & 7) << 4);
                bf16x8 bfr = *(bf16x8*)((char*)ldsF + byte);
#pragma unroll
                for (int kt = 0; kt < 4; ++kt)
                    acc[kt][ds] = __builtin_amdgcn_mfma_f32_16x16x32_bf16(afr[kt], bfr, acc[kt][ds], 0, 0, 0);
            }
        }
    }
#undef LOADCH

    float* Pb = P + (size_t)ms * (KC * DIM) + d0;
#pragma unroll
    for (int kt = 0; kt < 4; ++kt)
#pragma unroll
        for (int ds = 0; ds < 2; ++ds) {
            int d = wave * 32 + ds * 16 + l15;
#pragma unroll
            for (int r4 = 0; r4 < 4; ++r4) {
                int k = kt * 16 + lhi * 4 + r4;
                Pb[(size_t)k * DIM + d] = acc[kt][ds][r4];
            }
        }
}

// ---------------- K4: partial-reduce + mass-reduce + finalize centers -------------
__global__ __launch_bounds__(256) void k_final(const float* __restrict__ P,
                                               const float* __restrict__ PSGM,
                                               const float* __restrict__ cn,
                                               float* __restrict__ outC) {
    int k = blockIdx.x, tid = threadIdx.x;
    __shared__ float red[4];

    float msum = (tid < PSG_ROWS) ? PSGM[(size_t)tid * KC + k] : 0.f;
    for (int o = 32; o; o >>= 1) msum += __shfl_xor(msum, o);
    if ((tid & 63) == 0) red[tid >> 6] = msum;
    __syncthreads();
    float mk = fmaxf(red[0] + red[1] + red[2] + red[3], 1e-6f);
    __syncthreads();

    float w[3];
#pragma unroll
    for (int g = 0; g < 3; ++g) {
        int d = tid + g * 256;
        const float* pp = P + (size_t)k * DIM + d;
        float s0 = 0.f, s1 = 0.f, s2 = 0.f, s3 = 0.f;
        size_t stride = (size_t)KC * DIM;
#pragma unroll 4
        for (int msg = 0; msg < MSEG; msg += 4) {
            s0 += pp[(size_t)msg * stride];
            s1 += pp[(size_t)(msg + 1) * stride];
            s2 += pp[(size_t)(msg + 2) * stride];
            s3 += pp[(size_t)(msg + 3) * stride];
        }
        w[g] = ((s0 + s1) + (s2 + s3)) / mk;
    }

    float ss = w[0] * w[0] + w[1] * w[1] + w[2] * w[2];
    for (int o = 32; o; o >>= 1) ss += __shfl_xor(ss, o);
    if ((tid & 63) == 0) red[tid >> 6] = ss;
    __syncthreads();
    ss = red[0] + red[1] + red[2] + red[3];
    float n1 = fmaxf(sqrtf(ss), 1e-12f);
    __syncthreads();

    float u0 = 0.99f * cn[k * DIM + tid]       + 0.01f * (w[0] / n1);
    float u1 = 0.99f * cn[k * DIM + tid + 256] + 0.01f * (w[1] / n1);
    float u2 = 0.99f * cn[k * DIM + tid + 512] + 0.01f * (w[2] / n1);
    float ss2 = u0 * u0 + u1 * u1 + u2 * u2;
    for (int o = 32; o; o >>= 1) ss2 += __shfl_xor(ss2, o);
    if ((tid & 63) == 0) red[tid >> 6] = ss2;
    __syncthreads();
    ss2 = red[0] + red[1] + red[2] + red[3];
    float n2 = fmaxf(sqrtf(ss2), 1e-12f);

    outC[k * DIM + tid]       = u0 / n2;
    outC[k * DIM + tid + 256] = u1 / n2;
    outC[k * DIM + tid + 512] = u2 / n2;
}

extern "C" void kernel_launch(void* const* d_in, const int* in_sizes, int n_in,
                              void* d_out, int out_size, void* d_ws, size_t ws_size,
                              hipStream_t stream) {
    const float* F = (const float*)d_in[0];        // [65536][768]
    const float* centers = (const float*)d_in[1];  // [64][768]
    float* out = (float*)d_out;
    float* A = out;                                 // assignments [65536][64]
    float* outC = out + (size_t)M_TOTAL * KC;       // updated centers [64][768]

    float* w = (float*)d_ws;                        // ws = 768 MiB
    float* cn   = w;                                // 49152
    short* cnbf = (short*)(w + 49152);              // 24576 float slots
    float* R0   = w + 73728;                        // 64
    float* R1   = w + 73792;                        // 64
    float* invn = w + 74048;                        // 65536
    float* cbuf = w + 139584;                       // 65536
    float* E    = w + 205120;                       // 4194304 (pre-swizzled layout)
    short* Qbf  = (short*)(w + 4399424);            // 2097152 float slots (8 MiB)
    float* PSG  = w + 6496576;                      // 4 x [64][64] = 16384 floats
    float* PSG0 = PSG;
    float* PSG1 = PSG + 4096;
    float* PSG2 = PSG + 8192;
    float* PSGM = PSG + 12288;
    float* partial = w + 6520000;                   // MSEG*64*768 = 6291456 (24 MiB)

    k_centers<<<KC, 256, 0, stream>>>(centers, cn, cnbf, PSG);
    k_logits<<<LOGITS_BLOCKS, 256, 0, stream>>>(F, cnbf, E, invn, PSG0);
    k_sink<0><<<SINK_BLOCKS, 256, 0, stream>>>(E, nullptr, PSG0, invn, cbuf, PSG1, R0, A, Qbf);
    k_sink<1><<<SINK_BLOCKS, 256, 0, stream>>>(E, R0, PSG1, invn, cbuf, PSG2, R1, A, Qbf);
    k_sink<2><<<SINK_BLOCKS, 256, 0, stream>>>(E, R1, PSG2, invn, cbuf, PSGM, nullptr, A, Qbf);

    dim3 wgrid(DIM / DT, MSEG);
    k_weighted<<<wgrid, 256, 0, stream>>>(F, Qbf, partial);
    k_final<<<KC, 256, 0, stream>>>(partial, PSGM, cn, outC);
}